// Round 4
// baseline (489.481 us; speedup 1.0000x reference)
//
#include <hip/hip_runtime.h>
#include <hip/hip_bf16.h>
#include <stdint.h>
#include <stddef.h>

// Problem constants (from reference setup_inputs)
#define N_NODES 8192
#define DIM     256
#define BATCH   4096
#define CLASSES 1000
#define ALPHA_C 1.0f
#define BETA_C  0.01f
#define GAMMA_C 0.1f

// GEMM decomposition: mean(adj*(1-sim)) = (Sum[a] - <A*U, U>)/N^2 with U the
// row-normalized embeddings (sim = U U^T). W = A*U is an N x D GEMM in which
// adj is streamed through MFMA exactly once (256 MB -> ~44 us HBM floor).
#define KSPLIT  16
#define KRANGE  (N_NODES / KSPLIT)   // 512
#define NCHUNK  (KRANGE / 64)        // 8 chunks of BK=64
#define BM      64

typedef __bf16 bf16_t;
typedef __bf16 bf16x8 __attribute__((ext_vector_type(8)));
typedef float  f32x4  __attribute__((ext_vector_type(4)));
typedef float  f32x16 __attribute__((ext_vector_type(16)));

// Async global->LDS DMA, 16 B/lane, dest = wave-uniform base + lane*16.
__device__ __forceinline__ void async16(const void* g, void* l) {
  __builtin_amdgcn_global_load_lds(
      (const __attribute__((address_space(1))) uint32_t*)g,
      (__attribute__((address_space(3))) uint32_t*)l, 16, 0, 0);
}

// ---------------------------------------------------------------------------
// Prep: L2-normalize each embedding row (fp32 math); store U (row-major bf16)
// and V = U^T (256 x 8192 bf16, for the GEMM B-operand staging).
// ---------------------------------------------------------------------------
__global__ __launch_bounds__(256) void prep_kernel(
    const float* __restrict__ emb, bf16_t* __restrict__ U,
    bf16_t* __restrict__ V) {
  const int row = blockIdx.x;
  const int t = threadIdx.x;
  const float v = emb[(size_t)row * DIM + t];
  float sq = v * v;
  for (int off = 32; off; off >>= 1) sq += __shfl_down(sq, off);
  __shared__ float red[4];
  if ((t & 63) == 0) red[t >> 6] = sq;
  __syncthreads();
  const float total = red[0] + red[1] + red[2] + red[3];
  const bf16_t u = (bf16_t)(v * rsqrtf(total));
  U[(size_t)row * DIM + t] = u;
  V[(size_t)t * N_NODES + row] = u;  // scattered 2B; merged in L2, 4 MB total
}

// ---------------------------------------------------------------------------
// Cross-entropy: one block per batch row; single global pass, logits in regs.
// ---------------------------------------------------------------------------
__global__ __launch_bounds__(256) void ce_kernel(
    const float* __restrict__ pred, const int* __restrict__ target,
    float* __restrict__ out) {
  const int row = blockIdx.x;
  const int t = threadIdx.x;
  const float* p = pred + (size_t)row * CLASSES;

  float v[4];
  for (int k = 0; k < 4; ++k) {
    const int c = t + k * 256;
    v[k] = (c < CLASSES) ? p[c] : -INFINITY;
  }

  float m = fmaxf(fmaxf(v[0], v[1]), fmaxf(v[2], v[3]));
  for (int off = 32; off; off >>= 1) m = fmaxf(m, __shfl_down(m, off));

  __shared__ float red[8];
  const int wave = t >> 6, lane = t & 63;
  if (lane == 0) red[wave] = m;
  __syncthreads();
  if (t == 0) red[4] = fmaxf(fmaxf(red[0], red[1]), fmaxf(red[2], red[3]));
  __syncthreads();
  const float mx = red[4];

  float s = 0.f;
  for (int k = 0; k < 4; ++k) s += __expf(v[k] - mx);
  for (int off = 32; off; off >>= 1) s += __shfl_down(s, off);
  if (lane == 0) red[wave] = s;
  __syncthreads();
  if (t == 0) {
    float ssum = red[0] + red[1] + red[2] + red[3];
    float lse = mx + __logf(ssum);
    float loss = lse - p[target[row]];
    atomicAdd(out, loss * (ALPHA_C / (float)BATCH));
  }
}

// ---------------------------------------------------------------------------
// Fused: W = A_bf16 * U (BM=64 rows x D=256, K-split over 16), plus Sum[a],
// Sum[|a|] accumulated during the fp32->bf16 conversion, plus epilogue
// <W_tile, U_tile> -> single atomicAdd of the block's total contribution.
//
// LDS: As[64][64] bf16 (8 KB, XOR-swizzled 16B chunks: chunk c of row r at
// position c^(r&7)) + Bs[256 d][64 k] bf16 (32 KB, same swizzle) = 40 KB.
// 4 waves: wave w owns d-cols [w*64, w*64+64) x all 64 i-rows = 2x2 of
// v_mfma_f32_32x32x16_bf16 (64 AGPRs). A tile prefetched into 4 float4 regs.
// ---------------------------------------------------------------------------
__global__ __launch_bounds__(256) void gemm_kernel(
    const float* __restrict__ adj, const bf16_t* __restrict__ U,
    const bf16_t* __restrict__ V, float* __restrict__ out) {
  __shared__ __align__(16) bf16_t As[BM * 64];    // 8 KB
  __shared__ __align__(16) bf16_t Bs[DIM * 64];   // 32 KB

  const int i0 = blockIdx.x * BM;
  const int kbase = blockIdx.y * KRANGE;
  const int t = threadIdx.x;
  const int w = t >> 6, lane = t & 63;
  const int m = lane & 31, h = lane >> 5;

  // A staging: thread handles rows ar, ar+32, global k-chunk ac (16 B of bf16
  // = 8 fp32 = 2 float4), stored at swizzled position ac^(ar&7).
  const int ar = t >> 3;  // 0..31
  const int ac = t & 7;   // 0..7
  // B staging: lane -> (d-row srow, LDS position lane&7 holds global chunk
  // (lane&7)^(srow&7)).
  const int srow = lane >> 3;
  const int sch = (lane & 7) ^ srow;

  f32x16 acc[2][2] = {};
  float sa = 0.f, sabs = 0.f;

  // Prefetch chunk 0.
  float4 pf[4];
  {
    const float* a0p = adj + (size_t)(i0 + ar) * N_NODES + kbase + ac * 8;
    const float* a1p = adj + (size_t)(i0 + ar + 32) * N_NODES + kbase + ac * 8;
    pf[0] = *(const float4*)a0p;
    pf[1] = *(const float4*)(a0p + 4);
    pf[2] = *(const float4*)a1p;
    pf[3] = *(const float4*)(a1p + 4);
  }

  for (int kc = 0; kc < NCHUNK; ++kc) {
    const int k0 = kbase + kc * 64;

    // ---- write phase: convert A to bf16 (+ sum/abs-sum), stage B via DMA ---
    {
      bf16x8 c0, c1;
      c0[0] = (bf16_t)pf[0].x; c0[1] = (bf16_t)pf[0].y;
      c0[2] = (bf16_t)pf[0].z; c0[3] = (bf16_t)pf[0].w;
      c0[4] = (bf16_t)pf[1].x; c0[5] = (bf16_t)pf[1].y;
      c0[6] = (bf16_t)pf[1].z; c0[7] = (bf16_t)pf[1].w;
      c1[0] = (bf16_t)pf[2].x; c1[1] = (bf16_t)pf[2].y;
      c1[2] = (bf16_t)pf[2].z; c1[3] = (bf16_t)pf[2].w;
      c1[4] = (bf16_t)pf[3].x; c1[5] = (bf16_t)pf[3].y;
      c1[6] = (bf16_t)pf[3].z; c1[7] = (bf16_t)pf[3].w;
#pragma unroll
      for (int q = 0; q < 4; ++q) {
        sa += pf[q].x + pf[q].y + pf[q].z + pf[q].w;
        sabs += fabsf(pf[q].x) + fabsf(pf[q].y) +
                fabsf(pf[q].z) + fabsf(pf[q].w);
      }
      const int p = (ac ^ (ar & 7)) * 8;
      *(bf16x8*)&As[ar * 64 + p] = c0;
      *(bf16x8*)&As[(ar + 32) * 64 + p] = c1;
    }
#pragma unroll
    for (int s = 0; s < 8; ++s) {
      const int dbase = w * 64 + s * 8;  // wave-uniform
      async16(V + (size_t)(dbase + srow) * N_NODES + k0 + sch * 8,
              &Bs[dbase * 64]);
    }
    __syncthreads();

    // Prefetch next chunk's A while MFMAs run.
    if (kc + 1 < NCHUNK) {
      const int kn = k0 + 64;
      const float* a0p = adj + (size_t)(i0 + ar) * N_NODES + kn + ac * 8;
      const float* a1p = adj + (size_t)(i0 + ar + 32) * N_NODES + kn + ac * 8;
      pf[0] = *(const float4*)a0p;
      pf[1] = *(const float4*)(a0p + 4);
      pf[2] = *(const float4*)a1p;
      pf[3] = *(const float4*)(a1p + 4);
    }

    // ---- compute phase: 16 MFMAs per wave ----
#pragma unroll
    for (int kk = 0; kk < 4; ++kk) {
      const int p = ((kk * 2 + h) ^ (m & 7)) * 8;  // deswizzled position
      bf16x8 a0 = *(const bf16x8*)&As[m * 64 + p];
      bf16x8 a1 = *(const bf16x8*)&As[(m + 32) * 64 + p];
      bf16x8 b0 = *(const bf16x8*)&Bs[(w * 64 + m) * 64 + p];
      bf16x8 b1 = *(const bf16x8*)&Bs[(w * 64 + 32 + m) * 64 + p];
      acc[0][0] =
          __builtin_amdgcn_mfma_f32_32x32x16_bf16(a0, b0, acc[0][0], 0, 0, 0);
      acc[0][1] =
          __builtin_amdgcn_mfma_f32_32x32x16_bf16(a0, b1, acc[0][1], 0, 0, 0);
      acc[1][0] =
          __builtin_amdgcn_mfma_f32_32x32x16_bf16(a1, b0, acc[1][0], 0, 0, 0);
      acc[1][1] =
          __builtin_amdgcn_mfma_f32_32x32x16_bf16(a1, b1, acc[1][1], 0, 0, 0);
    }
    __syncthreads();
  }

  // Epilogue: simdot = <acc, U-tile>. C/D layout (32x32):
  // col = lane&31, row = (reg&3) + 8*(reg>>2) + 4*(lane>>5).
  float simdot = 0.f;
#pragma unroll
  for (int mi = 0; mi < 2; ++mi) {
#pragma unroll
    for (int nd = 0; nd < 2; ++nd) {
      const int ib = i0 + mi * 32 + 4 * h;
      const int d = w * 64 + nd * 32 + m;
      const bf16_t* up = U + (size_t)ib * DIM + d;
#pragma unroll
      for (int rg = 0; rg < 16; ++rg) {
        const int row = (rg & 3) + 8 * (rg >> 2);
        simdot += (float)up[(size_t)row * DIM] * acc[mi][nd][rg];
      }
    }
  }

  float local = BETA_C * sabs + GAMMA_C * (sa - simdot);
  for (int off = 32; off; off >>= 1) local += __shfl_down(local, off);
  float* redf = (float*)As;  // As dead after final barrier
  if (lane == 0) redf[w] = local;
  __syncthreads();
  if (t == 0) {
    const float inv = 1.f / ((float)N_NODES * (float)N_NODES);
    atomicAdd(out, (redf[0] + redf[1] + redf[2] + redf[3]) * inv);
  }
}

// ---------------------------------------------------------------------------
extern "C" void kernel_launch(void* const* d_in, const int* in_sizes, int n_in,
                              void* d_out, int out_size, void* d_ws,
                              size_t ws_size, hipStream_t stream) {
  const float* pred   = (const float*)d_in[0];
  const int*   target = (const int*)d_in[1];
  const float* adj    = (const float*)d_in[2];
  const float* emb    = (const float*)d_in[3];
  float* out = (float*)d_out;

  bf16_t* U = (bf16_t*)d_ws;                                   // 4 MB
  bf16_t* V = (bf16_t*)((char*)d_ws + (size_t)N_NODES * DIM * 2);  // 4 MB

  hipMemsetAsync(d_out, 0, sizeof(float), stream);
  prep_kernel<<<N_NODES, 256, 0, stream>>>(emb, U, V);
  ce_kernel<<<BATCH, 256, 0, stream>>>(pred, target, out);
  gemm_kernel<<<dim3(N_NODES / BM, KSPLIT), 256, 0, stream>>>(adj, U, V, out);
}

// Round 5
// 486.956 us; speedup vs baseline: 1.0052x; 1.0052x over previous
//
#include <hip/hip_runtime.h>
#include <hip/hip_bf16.h>
#include <stdint.h>
#include <stddef.h>

// Problem constants (from reference setup_inputs)
#define N_NODES 8192
#define DIM     256
#define BATCH   4096
#define CLASSES 1000
#define ALPHA_C 1.0f
#define BETA_C  0.01f
#define GAMMA_C 0.1f

// GEMM decomposition: mean(adj*(1-sim)) = (Sum[a] - <A*U, U>)/N^2 with U the
// row-normalized embeddings (sim = U U^T). W = A*U is an N x D GEMM in which
// adj is streamed through MFMA exactly once (268 MB -> ~43 us HBM floor).
#define KSPLIT  16
#define KRANGE  (N_NODES / KSPLIT)   // 512
#define NCHUNK  (KRANGE / 64)        // 8 chunks of BK=64
#define BM      64

typedef __bf16 bf16_t;
typedef __bf16 bf16x8 __attribute__((ext_vector_type(8)));
typedef float  f32x4  __attribute__((ext_vector_type(4)));
typedef float  f32x16 __attribute__((ext_vector_type(16)));

// Async global->LDS DMA, 16 B/lane, dest = wave-uniform base + lane*16.
__device__ __forceinline__ void async16(const void* g, void* l) {
  __builtin_amdgcn_global_load_lds(
      (const __attribute__((address_space(1))) uint32_t*)g,
      (__attribute__((address_space(3))) uint32_t*)l, 16, 0, 0);
}

// ---------------------------------------------------------------------------
// prep_norm: L2-normalize each embedding row (fp32 math), store U bf16
// (coalesced). No scattered writes here.
// ---------------------------------------------------------------------------
__global__ __launch_bounds__(256) void prep_norm(
    const float* __restrict__ emb, bf16_t* __restrict__ U) {
  const int row = blockIdx.x;
  const int t = threadIdx.x;
  const float v = emb[(size_t)row * DIM + t];
  float sq = v * v;
  for (int off = 32; off; off >>= 1) sq += __shfl_down(sq, off);
  __shared__ float red[4];
  if ((t & 63) == 0) red[t >> 6] = sq;
  __syncthreads();
  const float total = red[0] + red[1] + red[2] + red[3];
  U[(size_t)row * DIM + t] = (bf16_t)(v * rsqrtf(total));
}

// ---------------------------------------------------------------------------
// prep_transpose: V = U^T via 64x64 LDS tiles. 16 B coalesced on BOTH sides
// (full-cacheline stores -> no partial-line RMW amplification, unlike the
// scattered per-element stores of round 4).
// ---------------------------------------------------------------------------
#define TP 68  // padded LDS row stride (bf16 elems)

__global__ __launch_bounds__(256) void prep_transpose(
    const bf16_t* __restrict__ U, bf16_t* __restrict__ V) {
  __shared__ bf16_t tile[64 * TP];
  const int k0 = blockIdx.x * 64;  // node block
  const int d0 = blockIdx.y * 64;  // dim block
  const int t = threadIdx.x;
  const int r = t >> 3;            // 0..31
  const int c8 = t & 7;            // 16B chunk

  *(bf16x8*)&tile[r * TP + c8 * 8] =
      *(const bf16x8*)&U[(size_t)(k0 + r) * DIM + d0 + c8 * 8];
  *(bf16x8*)&tile[(r + 32) * TP + c8 * 8] =
      *(const bf16x8*)&U[(size_t)(k0 + r + 32) * DIM + d0 + c8 * 8];
  __syncthreads();

  bf16x8 o0, o1;
#pragma unroll
  for (int j = 0; j < 8; ++j) {
    o0[j] = tile[(c8 * 8 + j) * TP + r];
    o1[j] = tile[(c8 * 8 + j) * TP + r + 32];
  }
  *(bf16x8*)&V[(size_t)(d0 + r) * N_NODES + k0 + c8 * 8] = o0;
  *(bf16x8*)&V[(size_t)(d0 + r + 32) * N_NODES + k0 + c8 * 8] = o1;
}

// ---------------------------------------------------------------------------
// Cross-entropy: one block per batch row; single global pass, logits in regs.
// ---------------------------------------------------------------------------
__global__ __launch_bounds__(256) void ce_kernel(
    const float* __restrict__ pred, const int* __restrict__ target,
    float* __restrict__ out) {
  const int row = blockIdx.x;
  const int t = threadIdx.x;
  const float* p = pred + (size_t)row * CLASSES;

  float v[4];
  for (int k = 0; k < 4; ++k) {
    const int c = t + k * 256;
    v[k] = (c < CLASSES) ? p[c] : -INFINITY;
  }

  float m = fmaxf(fmaxf(v[0], v[1]), fmaxf(v[2], v[3]));
  for (int off = 32; off; off >>= 1) m = fmaxf(m, __shfl_down(m, off));

  __shared__ float red[8];
  const int wave = t >> 6, lane = t & 63;
  if (lane == 0) red[wave] = m;
  __syncthreads();
  if (t == 0) red[4] = fmaxf(fmaxf(red[0], red[1]), fmaxf(red[2], red[3]));
  __syncthreads();
  const float mx = red[4];

  float s = 0.f;
  for (int k = 0; k < 4; ++k) s += __expf(v[k] - mx);
  for (int off = 32; off; off >>= 1) s += __shfl_down(s, off);
  if (lane == 0) red[wave] = s;
  __syncthreads();
  if (t == 0) {
    float ssum = red[0] + red[1] + red[2] + red[3];
    float lse = mx + __logf(ssum);
    float loss = lse - p[target[row]];
    atomicAdd(out, loss * (ALPHA_C / (float)BATCH));
  }
}

// ---------------------------------------------------------------------------
// Fused: W = A_bf16 * U (BM=64 rows x D=256, K-split over 16), plus Sum[a],
// Sum[|a|] accumulated during the fp32->bf16 conversion, plus epilogue
// <W_tile, U_tile> -> single atomicAdd of the block's total contribution.
//
// LDS: As[64][64] bf16 (8 KB, XOR-swizzled 16B chunks: chunk c of row r at
// position c^(r&7)) + Bs[256 d][64 k] bf16 (32 KB, same swizzle) = 40 KB
// -> 4 blocks/CU. 4 waves: wave w owns d-cols [w*64, w*64+64) x all 64 rows
// = 2x2 of v_mfma_f32_32x32x16_bf16 (64 acc regs). A prefetched 1 chunk
// ahead in 4 float4 regs; B staged via global_load_lds issued BEFORE the A
// cvt so DMA flight overlaps the VALU conversion.
// ---------------------------------------------------------------------------
__global__ __launch_bounds__(256) void gemm_kernel(
    const float* __restrict__ adj, const bf16_t* __restrict__ U,
    const bf16_t* __restrict__ V, float* __restrict__ out) {
  __shared__ __align__(16) bf16_t As[BM * 64];    // 8 KB
  __shared__ __align__(16) bf16_t Bs[DIM * 64];   // 32 KB

  const int i0 = blockIdx.x * BM;
  const int kbase = blockIdx.y * KRANGE;
  const int t = threadIdx.x;
  const int w = t >> 6, lane = t & 63;
  const int m = lane & 31, h = lane >> 5;

  // A staging: thread handles rows ar, ar+32, k-chunk ac (16 B of bf16 =
  // 8 fp32 = 2 float4), stored at swizzled position ac^(ar&7).
  const int ar = t >> 3;  // 0..31
  const int ac = t & 7;   // 0..7
  // B staging: lane -> (d-row srow, LDS position lane&7 holds global chunk
  // (lane&7)^(srow&7)).
  const int srow = lane >> 3;
  const int sch = (lane & 7) ^ srow;

  f32x16 acc[2][2] = {};
  float sa = 0.f, sabs = 0.f;

  // Prefetch chunk 0.
  float4 pf[4];
  {
    const float* a0p = adj + (size_t)(i0 + ar) * N_NODES + kbase + ac * 8;
    const float* a1p = adj + (size_t)(i0 + ar + 32) * N_NODES + kbase + ac * 8;
    pf[0] = *(const float4*)a0p;
    pf[1] = *(const float4*)(a0p + 4);
    pf[2] = *(const float4*)a1p;
    pf[3] = *(const float4*)(a1p + 4);
  }

  for (int kc = 0; kc < NCHUNK; ++kc) {
    const int k0 = kbase + kc * 64;

    // ---- B DMA first (async, overlaps the A conversion below) ----
#pragma unroll
    for (int s = 0; s < 8; ++s) {
      const int dbase = w * 64 + s * 8;  // wave-uniform
      async16(V + (size_t)(dbase + srow) * N_NODES + k0 + sch * 8,
              &Bs[dbase * 64]);
    }

    // ---- convert A to bf16 (+ sum/abs-sum), write to LDS ----
    {
      bf16x8 c0, c1;
      c0[0] = (bf16_t)pf[0].x; c0[1] = (bf16_t)pf[0].y;
      c0[2] = (bf16_t)pf[0].z; c0[3] = (bf16_t)pf[0].w;
      c0[4] = (bf16_t)pf[1].x; c0[5] = (bf16_t)pf[1].y;
      c0[6] = (bf16_t)pf[1].z; c0[7] = (bf16_t)pf[1].w;
      c1[0] = (bf16_t)pf[2].x; c1[1] = (bf16_t)pf[2].y;
      c1[2] = (bf16_t)pf[2].z; c1[3] = (bf16_t)pf[2].w;
      c1[4] = (bf16_t)pf[3].x; c1[5] = (bf16_t)pf[3].y;
      c1[6] = (bf16_t)pf[3].z; c1[7] = (bf16_t)pf[3].w;
#pragma unroll
      for (int q = 0; q < 4; ++q) {
        sa += pf[q].x + pf[q].y + pf[q].z + pf[q].w;
        sabs += fabsf(pf[q].x) + fabsf(pf[q].y) +
                fabsf(pf[q].z) + fabsf(pf[q].w);
      }
      const int p = (ac ^ (ar & 7)) * 8;
      *(bf16x8*)&As[ar * 64 + p] = c0;
      *(bf16x8*)&As[(ar + 32) * 64 + p] = c1;
    }
    __syncthreads();

    // Prefetch next chunk's A while MFMAs run.
    if (kc + 1 < NCHUNK) {
      const int kn = k0 + 64;
      const float* a0p = adj + (size_t)(i0 + ar) * N_NODES + kn + ac * 8;
      const float* a1p = adj + (size_t)(i0 + ar + 32) * N_NODES + kn + ac * 8;
      pf[0] = *(const float4*)a0p;
      pf[1] = *(const float4*)(a0p + 4);
      pf[2] = *(const float4*)a1p;
      pf[3] = *(const float4*)(a1p + 4);
    }

    // ---- compute phase: 16 MFMAs per wave ----
#pragma unroll
    for (int kk = 0; kk < 4; ++kk) {
      const int p = ((kk * 2 + h) ^ (m & 7)) * 8;  // deswizzled position
      bf16x8 a0 = *(const bf16x8*)&As[m * 64 + p];
      bf16x8 a1 = *(const bf16x8*)&As[(m + 32) * 64 + p];
      bf16x8 b0 = *(const bf16x8*)&Bs[(w * 64 + m) * 64 + p];
      bf16x8 b1 = *(const bf16x8*)&Bs[(w * 64 + 32 + m) * 64 + p];
      acc[0][0] =
          __builtin_amdgcn_mfma_f32_32x32x16_bf16(a0, b0, acc[0][0], 0, 0, 0);
      acc[0][1] =
          __builtin_amdgcn_mfma_f32_32x32x16_bf16(a0, b1, acc[0][1], 0, 0, 0);
      acc[1][0] =
          __builtin_amdgcn_mfma_f32_32x32x16_bf16(a1, b0, acc[1][0], 0, 0, 0);
      acc[1][1] =
          __builtin_amdgcn_mfma_f32_32x32x16_bf16(a1, b1, acc[1][1], 0, 0, 0);
    }
    __syncthreads();
  }

  // Epilogue: simdot = <acc, U-tile>. C/D layout (32x32):
  // col = lane&31, row = (reg&3) + 8*(reg>>2) + 4*(lane>>5).
  float simdot = 0.f;
#pragma unroll
  for (int mi = 0; mi < 2; ++mi) {
#pragma unroll
    for (int nd = 0; nd < 2; ++nd) {
      const int ib = i0 + mi * 32 + 4 * h;
      const int d = w * 64 + nd * 32 + m;
      const bf16_t* up = U + (size_t)ib * DIM + d;
#pragma unroll
      for (int rg = 0; rg < 16; ++rg) {
        const int row = (rg & 3) + 8 * (rg >> 2);
        simdot += (float)up[(size_t)row * DIM] * acc[mi][nd][rg];
      }
    }
  }

  float local = BETA_C * sabs + GAMMA_C * (sa - simdot);
  for (int off = 32; off; off >>= 1) local += __shfl_down(local, off);
  float* redf = (float*)As;  // As dead after final barrier
  if (lane == 0) redf[w] = local;
  __syncthreads();
  if (t == 0) {
    const float inv = 1.f / ((float)N_NODES * (float)N_NODES);
    atomicAdd(out, (redf[0] + redf[1] + redf[2] + redf[3]) * inv);
  }
}

// ---------------------------------------------------------------------------
extern "C" void kernel_launch(void* const* d_in, const int* in_sizes, int n_in,
                              void* d_out, int out_size, void* d_ws,
                              size_t ws_size, hipStream_t stream) {
  const float* pred   = (const float*)d_in[0];
  const int*   target = (const int*)d_in[1];
  const float* adj    = (const float*)d_in[2];
  const float* emb    = (const float*)d_in[3];
  float* out = (float*)d_out;

  bf16_t* U = (bf16_t*)d_ws;                                       // 4 MB
  bf16_t* V = (bf16_t*)((char*)d_ws + (size_t)N_NODES * DIM * 2);  // 4 MB

  hipMemsetAsync(d_out, 0, sizeof(float), stream);
  ce_kernel<<<BATCH, 256, 0, stream>>>(pred, target, out);
  prep_norm<<<N_NODES, 256, 0, stream>>>(emb, U);
  prep_transpose<<<dim3(N_NODES / 64, DIM / 64), 256, 0, stream>>>(U, V);
  gemm_kernel<<<dim3(N_NODES / BM, KSPLIT), 256, 0, stream>>>(adj, U, V, out);
}